// Round 8
// baseline (270.850 us; speedup 1.0000x reference)
//
#include <hip/hip_runtime.h>
#include <hip/hip_fp8.h>
#include <stdint.h>
#include <cmath>

using f32x4  = __attribute__((ext_vector_type(4)))  float;
using f32x16 = __attribute__((ext_vector_type(16))) float;
using i32x4  = __attribute__((ext_vector_type(4)))  int;
using i32x8  = __attribute__((ext_vector_type(8)))  int;

#define FP8MAX 448.0f

// ---------------------------------------------------------------- helpers
__device__ __forceinline__ void gload_lds16(const void* g, void* l) {
  __builtin_amdgcn_global_load_lds(
      (const __attribute__((address_space(1))) unsigned int*)g,
      (__attribute__((address_space(3))) unsigned int*)l,
      16, 0, 0);
}

__device__ __forceinline__ uint8_t to_fp8(float v) {
  __hip_fp8_e4m3 q(fminf(fmaxf(v, -FP8MAX), FP8MAX));  // saturating RNE, OCP e4m3fn
  return q.__x;
}

// ---------------------------------------------------------------- W convert -> fp8 bytes (self-detecting)
// flag 2: float32 of fp8-exact values; 1: bf16; 0: raw fp8 bytes.
// Also zeroes the amax slot (stream-ordered before amax_kernel).
__global__ void wconv(const uint8_t* __restrict__ w, uint8_t* __restrict__ q,
                      unsigned int* __restrict__ amax_u, int n) {
  if (blockIdx.x == 0 && threadIdx.x == 0) amax_u[0] = 0u;

  const float* wf = (const float*)w;
  const unsigned short* wh = (const unsigned short*)w;
  int f32ok = 1, bf16ok = 1;
  for (int i = threadIdx.x; i < 4096; i += 256) {
    float v = wf[i];
    if (!(isfinite(v) && fabsf(v) <= FP8MAX)) f32ok = 0;
    else { __hip_fp8_e4m3 qq(v); if ((float)qq != v) f32ok = 0; }
    float hv = __uint_as_float(((unsigned int)wh[i]) << 16);
    if (!(isfinite(hv) && fabsf(hv) <= FP8MAX)) bf16ok = 0;
    else { __hip_fp8_e4m3 qh(hv); if ((float)qh != hv) bf16ok = 0; }
  }
  __shared__ int sf, sb;
  if (threadIdx.x == 0) { sf = 1; sb = 1; }
  __syncthreads();
  if (!f32ok) atomicAnd(&sf, 0);
  if (!bf16ok) atomicAnd(&sb, 0);
  __syncthreads();
  unsigned int f = sf ? 2u : (sb ? 1u : 0u);

  int i0 = (blockIdx.x * blockDim.x + threadIdx.x) * 4;
  if (i0 >= n) return;
  uint32_t out;
  if (f == 2) {
    float4 v = *(const float4*)((const float*)w + i0);
    out = (uint32_t)to_fp8(v.x) | ((uint32_t)to_fp8(v.y) << 8) |
          ((uint32_t)to_fp8(v.z) << 16) | ((uint32_t)to_fp8(v.w) << 24);
  } else if (f == 1) {
    ushort4 h = *(const ushort4*)((const unsigned short*)w + i0);
    float a = __uint_as_float(((unsigned int)h.x) << 16);
    float b = __uint_as_float(((unsigned int)h.y) << 16);
    float c = __uint_as_float(((unsigned int)h.z) << 16);
    float d = __uint_as_float(((unsigned int)h.w) << 16);
    out = (uint32_t)to_fp8(a) | ((uint32_t)to_fp8(b) << 8) |
          ((uint32_t)to_fp8(c) << 16) | ((uint32_t)to_fp8(d) << 24);
  } else {
    out = *(const uint32_t*)(w + i0);
  }
  *(uint32_t*)(q + i0) = out;
}

// ---------------------------------------------------------------- pass 1: amax = max(|x|)
__global__ void amax_kernel(const float* __restrict__ x, size_t n4,
                            unsigned int* __restrict__ amax_u) {
  const float4* x4 = (const float4*)x;
  float m = 0.0f;
  size_t stride = (size_t)gridDim.x * blockDim.x;
  for (size_t i = (size_t)blockIdx.x * blockDim.x + threadIdx.x; i < n4; i += stride) {
    float4 v = x4[i];
    m = fmaxf(m, fmaxf(fmaxf(fabsf(v.x), fabsf(v.y)),
                       fmaxf(fabsf(v.z), fabsf(v.w))));
  }
  #pragma unroll
  for (int off = 32; off > 0; off >>= 1)
    m = fmaxf(m, __shfl_xor(m, off));
  __shared__ float sm[16];
  int wid = threadIdx.x >> 6;
  if ((threadIdx.x & 63) == 0) sm[wid] = m;
  __syncthreads();
  if (threadIdx.x == 0) {
    int nw = blockDim.x >> 6;
    float r = sm[0];
    for (int i = 1; i < nw; i++) r = fmaxf(r, sm[i]);
    atomicMax(amax_u, __float_as_uint(r));  // non-negative float bits order-preserving
  }
}

// ---------------------------------------------------------------- pass 2: quantize x -> fp8
__global__ void quant_kernel(const float* __restrict__ x,
                             uint8_t* __restrict__ q,
                             const float* __restrict__ amax_p, size_t n16) {
  float amax = fmaxf(amax_p[0], 1e-12f);
  float scale = FP8MAX / amax;        // reference: FP8_MAX / clip(amax)
  const float4* x4 = (const float4*)x;
  uint4* q16 = (uint4*)q;
  size_t stride = (size_t)gridDim.x * blockDim.x;
  for (size_t i = (size_t)blockIdx.x * blockDim.x + threadIdx.x; i < n16; i += stride) {
    uint32_t w[4];
    #pragma unroll
    for (int j = 0; j < 4; j++) {
      float4 v = x4[i * 4 + j];
      w[j] = (uint32_t)to_fp8(v.x * scale) | ((uint32_t)to_fp8(v.y * scale) << 8) |
             ((uint32_t)to_fp8(v.z * scale) << 16) | ((uint32_t)to_fp8(v.w * scale) << 24);
    }
    uint4 o; o.x = w[0]; o.y = w[1]; o.z = w[2]; o.w = w[3];
    q16[i] = o;
  }
}

// ---------------------------------------------------------------- pass 3: MX-fp8 GEMM, 32x32x64 shape
// C[M,N] = s * A[M,K] x B[N,K]^T.  128x128 tile, BK=128, 4 waves (2x2,
// wave tile 64x64), mfma_scale_f32_32x32x64_f8f6f4 with E8M0 0x7F (=1.0).
// R7 was LDS-read-bound: 16x16x128 needs 1.5 KB LDS reads per 131K FLOP;
// 32x32x64 needs 1.0 KB (same operand bytes, 2x FLOP/instr) and halves
// MFMA issue count.
// A/B frag: row=lane&31, k=(lane>>5)*32+j (A==B bijection => exact).
// C/D frag (m74/m101): col=lane&31, row=(reg&3)+8*(reg>>2)+4*(lane>>5).
// T4: dbuf LDS + raw s_barrier + counted s_waitcnt vmcnt(8) (loads stay in
// flight across barriers).  T2 swizzle (rule #21): linear LDS dest, global
// source 16B-chunk ^= (row&7), reads XOR the same.  T5: setprio on MFMA.
#define BM 128
#define BN 128
#define BK 128

__global__ __launch_bounds__(256, 2) void gemm_fp8(
    const uint8_t* __restrict__ A,   // [M,K] fp8
    const uint8_t* __restrict__ B,   // [N,K] fp8
    float* __restrict__ C,           // [M,N] f32
    const float* __restrict__ amax_p,
    const float* __restrict__ wscale_p,
    int M, int N, int K) {
  __shared__ uint8_t lds[2][2][BM * BK];  // [dbuf][A/B][16 KB] = 64 KB

  // bijective XCD swizzle (gridDim % 8 == 0); 8 consecutive swz share bm
  // (same A-strip) -> same XCD -> strip fetched from HBM once per XCD.
  int nwg = gridDim.x;
  int cpx = nwg >> 3;
  int swz = (blockIdx.x & 7) * cpx + (blockIdx.x >> 3);

  int nstrips = N / BN;               // 8
  int bm = (swz / nstrips) * BM;
  int bn = (swz % nstrips) * BN;

  int t = threadIdx.x;                // 0..255
  int lane = t & 63;
  int wave = t >> 6;                  // 0..3
  int wm = (wave >> 1) * 64;          // 0,64
  int wn = (wave & 1) * 64;           // 0,64

  float amax = fmaxf(amax_p[0], 1e-12f);
  float scale = FP8MAX / amax;
  float s = (1.0f / scale) * wscale_p[0];   // inv_act_scale * weight_scale

  f32x16 acc[2][2] = {};

  // staging: 8 passes of 256x16B; pass p covers rows p*32 + (t>>3) of A (p<4)
  // or B (p>=4); 16B chunk ct = t&7.  LDS linear dest p*4096 + t*16;
  // global chunk pre-swizzled (ct ^ (row&7)).
  const int rt = t >> 3;
  const int ct = t & 7;

  // fragment read constants: frag rows wm|wn + fi*32 + (lane&31)
  const int lr = lane & 31;           // row-in-fragment
  const int x7 = lane & 7;            // row&7 for all frags
  const int hb = (lane >> 5) << 1;    // k-half chunk base within 4-chunk group
  int abase[2], bbase[2];
  #pragma unroll
  for (int i = 0; i < 2; i++) abase[i] = (wm + i * 32 + lr) * BK;
  #pragma unroll
  for (int j = 0; j < 2; j++) bbase[j] = (wn + j * 32 + lr) * BK;

  auto stage = [&](int buf, int kt) {   // 8 gload_lds per thread
    int k0 = kt * BK;
    #pragma unroll
    for (int p = 0; p < 4; ++p) {
      int r = p * 32 + rt;
      int gc = (ct ^ (r & 7)) * 16;
      gload_lds16(A + (size_t)(bm + r) * K + k0 + gc, &lds[buf][0][p * 4096 + t * 16]);
      gload_lds16(B + (size_t)(bn + r) * K + k0 + gc, &lds[buf][1][p * 4096 + t * 16]);
    }
  };

  auto compute = [&](int buf) {
    const uint8_t* baseA = &lds[buf][0][0];
    const uint8_t* baseB = &lds[buf][1][0];
    #pragma unroll
    for (int h = 0; h < 2; ++h) {       // mfma k-half: k = h*64
      const int c0 = ((h * 4 + hb) ^ x7) << 4;       // chunk (h*4 + hb)
      const int c1 = ((h * 4 + hb + 1) ^ x7) << 4;   // chunk (h*4 + hb + 1)
      i32x8 af[2], bf[2];
      #pragma unroll
      for (int i = 0; i < 2; i++) {
        i32x4 lo = *(const i32x4*)(baseA + abase[i] + c0);
        i32x4 hi = *(const i32x4*)(baseA + abase[i] + c1);
        af[i] = (i32x8){lo.x, lo.y, lo.z, lo.w, hi.x, hi.y, hi.z, hi.w};
      }
      #pragma unroll
      for (int j = 0; j < 2; j++) {
        i32x4 lo = *(const i32x4*)(baseB + bbase[j] + c0);
        i32x4 hi = *(const i32x4*)(baseB + bbase[j] + c1);
        bf[j] = (i32x8){lo.x, lo.y, lo.z, lo.w, hi.x, hi.y, hi.z, hi.w};
      }
      __builtin_amdgcn_s_setprio(1);
      #pragma unroll
      for (int i = 0; i < 2; i++)
        #pragma unroll
        for (int j = 0; j < 2; j++)
          acc[i][j] = __builtin_amdgcn_mfma_scale_f32_32x32x64_f8f6f4(
              af[i], bf[j], acc[i][j],
              0 /*A=fp8*/, 0 /*B=fp8*/,
              0, 0x7f7f7f7f,   // scale_A: E8M0 1.0
              0, 0x7f7f7f7f);  // scale_B: E8M0 1.0
      __builtin_amdgcn_s_setprio(0);
    }
  };

  const int KITERS = K / BK;          // 8
  stage(0, 0);                        // 8 loads in flight

  for (int it = 0; it < KITERS; ++it) {
    int cur = it & 1;
    if (it + 1 < KITERS) {
      stage(cur ^ 1, it + 1);                         // +8 loads (16 in flight)
      asm volatile("s_waitcnt vmcnt(8)" ::: "memory"); // cur's 8 landed; next's fly on
    } else {
      asm volatile("s_waitcnt vmcnt(0)" ::: "memory");
    }
    __builtin_amdgcn_s_barrier();        // all waves' cur loads landed
    __builtin_amdgcn_sched_barrier(0);   // pin ds_reads below the barrier
    compute(cur);
    __builtin_amdgcn_s_barrier();        // all waves done reading cur before overwrite
  }

  // epilogue: col=lane&31, row=(reg&3)+8*(reg>>2)+4*(lane>>5)
  #pragma unroll
  for (int i = 0; i < 2; i++) {
    #pragma unroll
    for (int j = 0; j < 2; j++) {
      int row0 = bm + wm + i * 32 + ((lane >> 5) << 2);
      int col = bn + wn + j * 32 + (lane & 31);
      #pragma unroll
      for (int r = 0; r < 16; r++) {
        int row = row0 + (r & 3) + ((r >> 2) << 3);
        C[(size_t)row * N + col] = acc[i][j][r] * s;
      }
    }
  }
}

// ---------------------------------------------------------------- launch
extern "C" void kernel_launch(void* const* d_in, const int* in_sizes, int n_in,
                              void* d_out, int out_size, void* d_ws, size_t ws_size,
                              hipStream_t stream) {
  const float* x = (const float*)d_in[0];
  const uint8_t* wraw = (const uint8_t*)d_in[1];
  const float* wscale = (const float*)d_in[2];
  float* out = (float*)d_out;

  long long in0 = in_sizes[0];   // M*K
  long long in1 = in_sizes[1];   // N*K
  double kd = sqrt((double)in0 * (double)in1 / (double)out_size);
  long long K = (long long)(kd + 0.5);
  long long M = in0 / K;
  long long N = in1 / K;

  // ws layout: [0,4) amax | [4096,+1MB) qw | [2MB,+64MB) qx
  unsigned int* amax_u = (unsigned int*)d_ws;
  const float* amax_f = (const float*)d_ws;
  uint8_t* qw = (uint8_t*)d_ws + 4096;
  uint8_t* qx = (uint8_t*)d_ws + (2u << 20);

  wconv<<<(unsigned)(in1 / 4 / 256), 256, 0, stream>>>(wraw, qw, amax_u, (int)in1);
  amax_kernel<<<2048, 256, 0, stream>>>(x, (size_t)(in0 / 4), amax_u);
  quant_kernel<<<2048, 256, 0, stream>>>(x, qx, amax_f, (size_t)(in0 / 16));

  dim3 grid((unsigned)((M / BM) * (N / BN)));
  gemm_fp8<<<grid, 256, 0, stream>>>(qx, qw, out, amax_f, wscale,
                                     (int)M, (int)N, (int)K);
}

// Round 9
// 260.247 us; speedup vs baseline: 1.0407x; 1.0407x over previous
//
#include <hip/hip_runtime.h>
#include <hip/hip_fp8.h>
#include <stdint.h>
#include <cmath>

using f32x4  = __attribute__((ext_vector_type(4)))  float;
using f32x16 = __attribute__((ext_vector_type(16))) float;
using i32x4  = __attribute__((ext_vector_type(4)))  int;
using i32x8  = __attribute__((ext_vector_type(8)))  int;

#define FP8MAX 448.0f

// ---------------------------------------------------------------- helpers
__device__ __forceinline__ void gload_lds16(const void* g, void* l) {
  __builtin_amdgcn_global_load_lds(
      (const __attribute__((address_space(1))) unsigned int*)g,
      (__attribute__((address_space(3))) unsigned int*)l,
      16, 0, 0);
}

__device__ __forceinline__ uint8_t to_fp8(float v) {
  __hip_fp8_e4m3 q(fminf(fmaxf(v, -FP8MAX), FP8MAX));  // saturating RNE, OCP e4m3fn
  return q.__x;
}

// ---------------------------------------------------------------- W convert -> fp8 bytes (self-detecting)
// flag 2: float32 of fp8-exact values; 1: bf16; 0: raw fp8 bytes.
// Also zeroes the amax slot (stream-ordered before amax_kernel).
__global__ void wconv(const uint8_t* __restrict__ w, uint8_t* __restrict__ q,
                      unsigned int* __restrict__ amax_u, int n) {
  if (blockIdx.x == 0 && threadIdx.x == 0) amax_u[0] = 0u;

  const float* wf = (const float*)w;
  const unsigned short* wh = (const unsigned short*)w;
  int f32ok = 1, bf16ok = 1;
  for (int i = threadIdx.x; i < 4096; i += 256) {
    float v = wf[i];
    if (!(isfinite(v) && fabsf(v) <= FP8MAX)) f32ok = 0;
    else { __hip_fp8_e4m3 qq(v); if ((float)qq != v) f32ok = 0; }
    float hv = __uint_as_float(((unsigned int)wh[i]) << 16);
    if (!(isfinite(hv) && fabsf(hv) <= FP8MAX)) bf16ok = 0;
    else { __hip_fp8_e4m3 qh(hv); if ((float)qh != hv) bf16ok = 0; }
  }
  __shared__ int sf, sb;
  if (threadIdx.x == 0) { sf = 1; sb = 1; }
  __syncthreads();
  if (!f32ok) atomicAnd(&sf, 0);
  if (!bf16ok) atomicAnd(&sb, 0);
  __syncthreads();
  unsigned int f = sf ? 2u : (sb ? 1u : 0u);

  int i0 = (blockIdx.x * blockDim.x + threadIdx.x) * 4;
  if (i0 >= n) return;
  uint32_t out;
  if (f == 2) {
    float4 v = *(const float4*)((const float*)w + i0);
    out = (uint32_t)to_fp8(v.x) | ((uint32_t)to_fp8(v.y) << 8) |
          ((uint32_t)to_fp8(v.z) << 16) | ((uint32_t)to_fp8(v.w) << 24);
  } else if (f == 1) {
    ushort4 h = *(const ushort4*)((const unsigned short*)w + i0);
    float a = __uint_as_float(((unsigned int)h.x) << 16);
    float b = __uint_as_float(((unsigned int)h.y) << 16);
    float c = __uint_as_float(((unsigned int)h.z) << 16);
    float d = __uint_as_float(((unsigned int)h.w) << 16);
    out = (uint32_t)to_fp8(a) | ((uint32_t)to_fp8(b) << 8) |
          ((uint32_t)to_fp8(c) << 16) | ((uint32_t)to_fp8(d) << 24);
  } else {
    out = *(const uint32_t*)(w + i0);
  }
  *(uint32_t*)(q + i0) = out;
}

// ---------------------------------------------------------------- pass 1: amax = max(|x|)
__global__ void amax_kernel(const float* __restrict__ x, size_t n4,
                            unsigned int* __restrict__ amax_u) {
  const float4* x4 = (const float4*)x;
  float m = 0.0f;
  size_t stride = (size_t)gridDim.x * blockDim.x;
  for (size_t i = (size_t)blockIdx.x * blockDim.x + threadIdx.x; i < n4; i += stride) {
    float4 v = x4[i];
    m = fmaxf(m, fmaxf(fmaxf(fabsf(v.x), fabsf(v.y)),
                       fmaxf(fabsf(v.z), fabsf(v.w))));
  }
  #pragma unroll
  for (int off = 32; off > 0; off >>= 1)
    m = fmaxf(m, __shfl_xor(m, off));
  __shared__ float sm[16];
  int wid = threadIdx.x >> 6;
  if ((threadIdx.x & 63) == 0) sm[wid] = m;
  __syncthreads();
  if (threadIdx.x == 0) {
    int nw = blockDim.x >> 6;
    float r = sm[0];
    for (int i = 1; i < nw; i++) r = fmaxf(r, sm[i]);
    atomicMax(amax_u, __float_as_uint(r));  // non-negative float bits order-preserving
  }
}

// ---------------------------------------------------------------- pass 2: quantize x -> fp8
__global__ void quant_kernel(const float* __restrict__ x,
                             uint8_t* __restrict__ q,
                             const float* __restrict__ amax_p, size_t n16) {
  float amax = fmaxf(amax_p[0], 1e-12f);
  float scale = FP8MAX / amax;        // reference: FP8_MAX / clip(amax)
  const float4* x4 = (const float4*)x;
  uint4* q16 = (uint4*)q;
  size_t stride = (size_t)gridDim.x * blockDim.x;
  for (size_t i = (size_t)blockIdx.x * blockDim.x + threadIdx.x; i < n16; i += stride) {
    uint32_t w[4];
    #pragma unroll
    for (int j = 0; j < 4; j++) {
      float4 v = x4[i * 4 + j];
      w[j] = (uint32_t)to_fp8(v.x * scale) | ((uint32_t)to_fp8(v.y * scale) << 8) |
             ((uint32_t)to_fp8(v.z * scale) << 16) | ((uint32_t)to_fp8(v.w * scale) << 24);
    }
    uint4 o; o.x = w[0]; o.y = w[1]; o.z = w[2]; o.w = w[3];
    q16[i] = o;
  }
}

// ---------------------------------------------------------------- pass 3: MX-fp8 GEMM, deep-pipelined 2-phase/K-tile
// C[M,N] = s * A[M,K] x B[N,K]^T.  256x256 tile, BK=64, 8 waves (2M x 4N,
// wave tile 128x64, 4x2 frags), mfma_scale_f32_32x32x64_f8f6f4, E8M0 0x7F.
// m201-style schedule: quad-buffered LDS (128 KB), prefetch depth 3,
// entry s_waitcnt vmcnt(8) NEVER drains in steady state (tail 8->4->0).
// Per K-tile: 2 phases (N-column split); each {ds_read, stage-half of tile
// t+3, lgkmcnt(0)+sched_barrier, setprio-wrapped 4x MFMA}.
// T2 swizzle for BK=64 (rule #21): LDS dest linear, global source 16B-chunk
// ^= (row>>1)&3, reads XOR the same.
#define BM 256
#define BN 256
#define BK 64
#define NBUF 4

__global__ __launch_bounds__(512, 2) void gemm_fp8(
    const uint8_t* __restrict__ A,   // [M,K] fp8
    const uint8_t* __restrict__ B,   // [N,K] fp8
    float* __restrict__ C,           // [M,N] f32
    const float* __restrict__ amax_p,
    const float* __restrict__ wscale_p,
    int M, int N, int K) {
  __shared__ uint8_t ldsA[NBUF][BM * BK];  // 4 x 16 KB
  __shared__ uint8_t ldsB[NBUF][BN * BK];  // 4 x 16 KB   (128 KB total)

  // bijective XCD swizzle (gridDim % 8 == 0); consecutive swz share bm in
  // groups of 4 -> A-strip read once per XCD from HBM, rest L2 hits.
  int nwg = gridDim.x;
  int cpx = nwg >> 3;
  int swz = (blockIdx.x & 7) * cpx + (blockIdx.x >> 3);

  int nstrips = N / BN;               // 4
  int bm = (swz / nstrips) * BM;
  int bn = (swz % nstrips) * BN;

  int t = threadIdx.x;                // 0..511
  int lane = t & 63;
  int wave = t >> 6;                  // 0..7
  int wm = (wave >> 2) * 128;         // 0,128
  int wn = (wave & 3) * 64;           // 0,64,128,192

  float amax = fmaxf(amax_p[0], 1e-12f);
  float scale = FP8MAX / amax;
  float s = (1.0f / scale) * wscale_p[0];   // inv_act_scale * weight_scale

  f32x16 acc[4][2] = {};

  // staging: thread t -> rows {srow, 128+srow}, chunk sc of a 256x64B tile;
  // LDS linear dest l*8192 + t*16 (row-major == t*16 exactly);
  // global chunk pre-swizzled sc ^ ((row>>1)&3)  [row>>1 mod 4 == srow>>1 mod 4]
  const int srow = t >> 2;            // 0..127
  const int sc = t & 3;
  const int gsw = (sc ^ ((srow >> 1) & 3)) * 16;

  // fragment read constants: rows wm|wn + f*32 + (lane&31)
  const int lr = lane & 31;
  const int kh = lane >> 5;                 // k-half: k = kh*32 + j
  const int rsw = (lr >> 1) & 3;            // (row>>1)&3 for all frag rows
  const int cR0 = ((2 * kh) ^ rsw) << 4;    // first 16B chunk (swizzled)
  const int cR1 = ((2 * kh + 1) ^ rsw) << 4;

  const int NT = K / BK;              // 16

  auto stageA = [&](int buf, int kt) {      // 2 gload_lds
    const uint8_t* g = A + (size_t)kt * BK + gsw;
    #pragma unroll
    for (int l = 0; l < 2; ++l)
      gload_lds16(g + (size_t)(bm + l * 128 + srow) * K,
                  &ldsA[buf][l * 8192 + t * 16]);
  };
  auto stageB = [&](int buf, int kt) {      // 2 gload_lds
    const uint8_t* g = B + (size_t)kt * BK + gsw;
    #pragma unroll
    for (int l = 0; l < 2; ++l)
      gload_lds16(g + (size_t)(bn + l * 128 + srow) * K,
                  &ldsB[buf][l * 8192 + t * 16]);
  };

  // prologue: tiles 0,1,2 in flight (12 loads/thread)
  stageA(0, 0); stageB(0, 0);
  if (NT > 1) { stageA(1, 1); stageB(1, 1); }
  if (NT > 2) { stageA(2, 2); stageB(2, 2); }

  for (int tt = 0; tt < NT; ++tt) {
    int buf = tt & (NBUF - 1);
    // entry wait: tile tt's 4 loads landed; later tiles' stay in flight
    if (tt + 2 < NT)      asm volatile("s_waitcnt vmcnt(8)" ::: "memory");
    else if (tt + 1 < NT) asm volatile("s_waitcnt vmcnt(4)" ::: "memory");
    else                  asm volatile("s_waitcnt vmcnt(0)" ::: "memory");
    __builtin_amdgcn_s_barrier();        // cross-wave: everyone's tile-tt loads landed
    __builtin_amdgcn_sched_barrier(0);   // pin all reads/stages below the barrier

    const uint8_t* bA = &ldsA[buf][0];
    const uint8_t* bB = &ldsB[buf][0];

    // ---- phase A: af[0..3] + bf0; mfma column 0
    i32x8 af[4], bf;
    #pragma unroll
    for (int i = 0; i < 4; i++) {
      const uint8_t* p = bA + (wm + i * 32 + lr) * BK;
      i32x4 lo = *(const i32x4*)(p + cR0);
      i32x4 hi = *(const i32x4*)(p + cR1);
      af[i] = (i32x8){lo.x, lo.y, lo.z, lo.w, hi.x, hi.y, hi.z, hi.w};
    }
    {
      const uint8_t* p = bB + (wn + lr) * BK;
      i32x4 lo = *(const i32x4*)(p + cR0);
      i32x4 hi = *(const i32x4*)(p + cR1);
      bf = (i32x8){lo.x, lo.y, lo.z, lo.w, hi.x, hi.y, hi.z, hi.w};
    }
    if (tt + 3 < NT) stageA((tt + 3) & (NBUF - 1), tt + 3);
    asm volatile("s_waitcnt lgkmcnt(0)" ::: "memory");
    __builtin_amdgcn_sched_barrier(0);
    __builtin_amdgcn_s_setprio(1);
    #pragma unroll
    for (int i = 0; i < 4; i++)
      acc[i][0] = __builtin_amdgcn_mfma_scale_f32_32x32x64_f8f6f4(
          af[i], bf, acc[i][0], 0, 0, 0, 0x7f7f7f7f, 0, 0x7f7f7f7f);
    __builtin_amdgcn_s_setprio(0);
    __builtin_amdgcn_s_barrier();        // phase boundary

    // ---- phase B: bf1 (af held in reg); mfma column 1
    {
      const uint8_t* p = bB + (wn + 32 + lr) * BK;
      i32x4 lo = *(const i32x4*)(p + cR0);
      i32x4 hi = *(const i32x4*)(p + cR1);
      bf = (i32x8){lo.x, lo.y, lo.z, lo.w, hi.x, hi.y, hi.z, hi.w};
    }
    if (tt + 3 < NT) stageB((tt + 3) & (NBUF - 1), tt + 3);
    asm volatile("s_waitcnt lgkmcnt(0)" ::: "memory");
    __builtin_amdgcn_sched_barrier(0);
    __builtin_amdgcn_s_setprio(1);
    #pragma unroll
    for (int i = 0; i < 4; i++)
      acc[i][1] = __builtin_amdgcn_mfma_scale_f32_32x32x64_f8f6f4(
          af[i], bf, acc[i][1], 0, 0, 0, 0x7f7f7f7f, 0, 0x7f7f7f7f);
    __builtin_amdgcn_s_setprio(0);
    // no trailing barrier: next iter's entry barrier covers it (readers of
    // any buf finish via their own lgkmcnt(0) before reaching that barrier)
  }

  // epilogue: col=lane&31, row=(reg&3)+8*(reg>>2)+4*(lane>>5)  (verified R8)
  #pragma unroll
  for (int i = 0; i < 4; i++) {
    #pragma unroll
    for (int j = 0; j < 2; j++) {
      int row0 = bm + wm + i * 32 + (kh << 2);
      int col = bn + wn + j * 32 + lr;
      #pragma unroll
      for (int r = 0; r < 16; r++) {
        int row = row0 + (r & 3) + ((r >> 2) << 3);
        C[(size_t)row * N + col] = acc[i][j][r] * s;
      }
    }
  }
}

// ---------------------------------------------------------------- launch
extern "C" void kernel_launch(void* const* d_in, const int* in_sizes, int n_in,
                              void* d_out, int out_size, void* d_ws, size_t ws_size,
                              hipStream_t stream) {
  const float* x = (const float*)d_in[0];
  const uint8_t* wraw = (const uint8_t*)d_in[1];
  const float* wscale = (const float*)d_in[2];
  float* out = (float*)d_out;

  long long in0 = in_sizes[0];   // M*K
  long long in1 = in_sizes[1];   // N*K
  double kd = sqrt((double)in0 * (double)in1 / (double)out_size);
  long long K = (long long)(kd + 0.5);
  long long M = in0 / K;
  long long N = in1 / K;

  // ws layout: [0,4) amax | [4096,+1MB) qw | [2MB,+64MB) qx
  unsigned int* amax_u = (unsigned int*)d_ws;
  const float* amax_f = (const float*)d_ws;
  uint8_t* qw = (uint8_t*)d_ws + 4096;
  uint8_t* qx = (uint8_t*)d_ws + (2u << 20);

  wconv<<<(unsigned)(in1 / 4 / 256), 256, 0, stream>>>(wraw, qw, amax_u, (int)in1);
  amax_kernel<<<2048, 256, 0, stream>>>(x, (size_t)(in0 / 4), amax_u);
  quant_kernel<<<2048, 256, 0, stream>>>(x, qx, amax_f, (size_t)(in0 / 16));

  dim3 grid((unsigned)((M / BM) * (N / BN)));
  gemm_fp8<<<grid, 512, 0, stream>>>(qx, qw, out, amax_f, wscale,
                                     (int)M, (int)N, (int)K);
}